// Round 11
// baseline (2323.616 us; speedup 1.0000x reference)
//
#include <hip/hip_runtime.h>
#include <math.h>

#define N_GENES 3000
#define N_CELLS 4096
#define GPAD    3072
#define INTER_R 512
#define EMBD_R  128
#define INTER_C 1024
#define EMBD_C  256
#define KNN_E   65536
#define PPI_E   262144

typedef unsigned short u16;
typedef __bf16 bf16x8 __attribute__((ext_vector_type(8)));
typedef float f32x4 __attribute__((ext_vector_type(4)));

__device__ __forceinline__ float b2f(u16 u) {
  union { unsigned i; float f; } x; x.i = ((unsigned)u) << 16; return x.f;
}
__device__ __forceinline__ u16 f2b(float f) {
  union { float f; unsigned i; } x; x.f = f;
  unsigned r = (x.i + 0x7FFFu + ((x.i >> 16) & 1u)) >> 16;
  return (u16)r;
}

typedef const void __attribute__((address_space(1))) gvoid;
typedef void __attribute__((address_space(3))) svoid;
__device__ __forceinline__ void gload16(const void* g, void* l) {
  __builtin_amdgcn_global_load_lds((gvoid*)g, (svoid*)l, 16, 0, 0);
}

// ---------------------------------------------------------------------------
// 8-phase MFMA bf16 GEMM, tile TM x 256 where TM = MF*32 (MF=6: 192).
// C[M,N] = act((accum?C:0) + A[M,K]@BT[N,K]^T + (biasRow?bias[m]:bias[n])).
// K % 64 == 0, K/64 >= 3.  512 thr = 8 waves (2M x 4N), wave = (MF*16) x 64.
// R7-proven config: 192x256 tiles -> 16x16 = 256 blocks for M=3000, N=4096
// (exactly 1 block/CU on all 256 CUs).  LDS 112KB.  Region layout
// [rows][4 slots x 16B], slot = khi ^ ((row>>1)&3) (measured-0-conflict).
// Counted vmcnt once per K-tile (waves 0-3: 6, waves 4-7: 4); raw barriers;
// setprio around MFMA.
template <int OUTF32, int MF>
__global__ __launch_bounds__(512, 1) void mgemm8_k(
    const u16* __restrict__ A, int lda, const u16* __restrict__ BT, int ldb,
    const float* __restrict__ bias, int biasRow, void* __restrict__ Cv, int ldc,
    int M, int N, int K, int accum, int act, int nbx) {
  constexpr int MFH = MF / 2;
  constexpr int TM = MF * 32;
  constexpr int ABYTES = TM * 64;
  constexpr int BBYTES = 16384;
  constexpr int BUFB = 2 * ABYTES + 2 * BBYTES;
  __shared__ char S[2 * BUFB];
  const int t = threadIdx.x;
  const int wid = t >> 6;
  const int l = t & 63;
  const int wm = wid >> 2, wn = wid & 3;
  const int fr = l & 15, hi = l >> 4;

  // bijective XCD swizzle (m204)
  int nwg = gridDim.x, bid = blockIdx.x;
  int q = nwg >> 3, r = nwg & 7, xcd = bid & 7, seq = bid >> 3;
  int sid = (xcd < r ? xcd * (q + 1) : r * (q + 1) + (xcd - r) * q) + seq;
  int by = sid / nbx, bx = sid - by * nbx;
  const int row0 = by * TM, col0 = bx * 256;

  f32x4 acc[MF][4];
#pragma unroll
  for (int i = 0; i < MF; i++)
#pragma unroll
    for (int jj = 0; jj < 4; jj++) acc[i][jj] = (f32x4){0.f, 0.f, 0.f, 0.f};

  // staging chunk mapping: chunk c -> row=c>>2, slot=c&3, logical g=slot^((row>>1)&3)
  const int cA1 = t, cA2 = t + 512;
  const int rA1 = cA1 >> 2, rA2 = cA2 >> 2;
  const int gA1 = (cA1 & 3) ^ ((rA1 >> 1) & 3);
  const int gA2 = (cA2 & 3) ^ ((rA2 >> 1) & 3);
  int arow1 = row0 + rA1; arow1 = arow1 < M ? arow1 : M - 1;
  int arow2 = row0 + (rA2 < TM ? rA2 : TM - 1); arow2 = arow2 < M ? arow2 : M - 1;
  const u16* baseA1 = A + (size_t)arow1 * lda + gA1 * 8;
  const u16* baseA2 = A + (size_t)arow2 * lda + gA2 * 8;
  const bool doA2 = (MF == 8) || (t < 256);
  int brow1 = col0 + rA1; brow1 = brow1 < N ? brow1 : N - 1;
  int brow2 = col0 + rA2; brow2 = brow2 < N ? brow2 : N - 1;
  const u16* baseB1 = BT + (size_t)brow1 * ldb + gA1 * 8;
  const u16* baseB2 = BT + (size_t)brow2 * ldb + gA2 * 8;

  auto aoff = [](int buf, int kh) { return buf * BUFB + kh * ABYTES; };
  auto boff = [](int buf, int kh) { return buf * BUFB + 2 * ABYTES + kh * BBYTES; };

  auto stageA = [&](int buf, int kh, int kt) {
    int ko = kt * 64 + kh * 32;
    gload16(baseA1 + ko, S + aoff(buf, kh) + cA1 * 16);
    if (doA2) gload16(baseA2 + ko, S + aoff(buf, kh) + cA2 * 16);
  };
  auto stageB = [&](int buf, int kh, int kt) {
    int ko = kt * 64 + kh * 32;
    gload16(baseB1 + ko, S + boff(buf, kh) + cA1 * 16);
    gload16(baseB2 + ko, S + boff(buf, kh) + cA2 * 16);
  };

  bf16x8 af[MFH], bfr[4];
  auto dsrA = [&](int buf, int kh, int mh) {
#pragma unroll
    for (int i = 0; i < MFH; i++) {
      int row = wm * (MF * 16) + (mh * MFH + i) * 16 + fr;
      af[i] = *(const bf16x8*)(S + aoff(buf, kh) + row * 64 +
                               ((hi ^ ((row >> 1) & 3)) << 4));
    }
  };
  auto dsrB = [&](int buf, int kh) {
#pragma unroll
    for (int i = 0; i < 4; i++) {
      int row = wn * 64 + i * 16 + fr;
      bfr[i] = *(const bf16x8*)(S + boff(buf, kh) + row * 64 +
                                ((hi ^ ((row >> 1) & 3)) << 4));
    }
  };
  auto mma = [&](int mh) {
    __builtin_amdgcn_s_setprio(1);
#pragma unroll
    for (int i = 0; i < MFH; i++)
#pragma unroll
      for (int jj = 0; jj < 4; jj++)
        acc[mh * MFH + i][jj] = __builtin_amdgcn_mfma_f32_16x16x32_bf16(
            af[i], bfr[jj], acc[mh * MFH + i][jj], 0, 0, 0);
    __builtin_amdgcn_s_setprio(0);
  };
  auto vmw = [&]() {
    if (MF == 6 && wid >= 4)
      asm volatile("s_waitcnt vmcnt(4)" ::: "memory");
    else
      asm volatile("s_waitcnt vmcnt(6)" ::: "memory");
  };
  auto barmid = [&]() {
    __builtin_amdgcn_sched_barrier(0);
    __builtin_amdgcn_s_barrier();
    asm volatile("s_waitcnt lgkmcnt(0)" ::: "memory");
    __builtin_amdgcn_sched_barrier(0);
  };
  auto barend = [&]() {
    __builtin_amdgcn_sched_barrier(0);
    __builtin_amdgcn_s_barrier();
    __builtin_amdgcn_sched_barrier(0);
  };

  const int nt = K >> 6;
  // prologue: tile0 full + tile1 {A0,B0,A1}
  stageA(0, 0, 0); stageB(0, 0, 0); stageA(0, 1, 0); stageB(0, 1, 0);
  stageA(1, 0, 1); stageB(1, 0, 1); stageA(1, 1, 1);
  vmw();
  __builtin_amdgcn_sched_barrier(0);
  __builtin_amdgcn_s_barrier();
  __builtin_amdgcn_sched_barrier(0);

  int p = 0;
  for (int kt = 0; kt < nt - 2; kt++, p ^= 1) {
    dsrA(p, 0, 0); dsrB(p, 0);
    stageB(p ^ 1, 1, kt + 1);
    barmid(); mma(0); barend();
    dsrA(p, 0, 1);
    stageA(p, 0, kt + 2);
    barmid(); mma(1); barend();
    dsrA(p, 1, 0); dsrB(p, 1);
    stageB(p, 0, kt + 2);
    barmid(); mma(0); barend();
    dsrA(p, 1, 1);
    stageA(p, 1, kt + 2);
    vmw();
    barmid(); mma(1); barend();
  }
  // peeled kt = nt-2
  dsrA(p, 0, 0); dsrB(p, 0);
  stageB(p ^ 1, 1, nt - 1);
  barmid(); mma(0); barend();
  dsrA(p, 0, 1);
  barmid(); mma(1); barend();
  dsrA(p, 1, 0); dsrB(p, 1);
  barmid(); mma(0); barend();
  dsrA(p, 1, 1);
  asm volatile("s_waitcnt vmcnt(0)" ::: "memory");
  barmid(); mma(1); barend();
  p ^= 1;
  // peeled kt = nt-1
  dsrA(p, 0, 0); dsrB(p, 0);
  barmid(); mma(0); barend();
  dsrA(p, 0, 1);
  barmid(); mma(1); barend();
  dsrA(p, 1, 0); dsrB(p, 1);
  barmid(); mma(0); barend();
  dsrA(p, 1, 1);
  barmid(); mma(1); barend();

#pragma unroll
  for (int mf = 0; mf < MF; mf++) {
    int mb = row0 + wm * (MF * 16) + mf * 16 + hi * 4;
#pragma unroll
    for (int rr2 = 0; rr2 < 4; rr2++) {
      int m = mb + rr2;
      if (m >= M) continue;
#pragma unroll
      for (int nf = 0; nf < 4; nf++) {
        int n = col0 + wn * 64 + nf * 16 + fr;
        if (n >= N) continue;
        float v = acc[mf][nf][rr2];
        if (bias) v += biasRow ? bias[m] : bias[n];
        if (OUTF32) {
          float* C = (float*)Cv;
          if (accum) v += C[(size_t)m * ldc + n];
          if (act == 1) v = v > 0.f ? v : 0.01f * v;
          else if (act == 2) v = fmaxf(v, 0.f);
          C[(size_t)m * ldc + n] = v;
        } else {
          u16* C = (u16*)Cv;
          if (accum) v += b2f(C[(size_t)m * ldc + n]);
          if (act == 1) v = v > 0.f ? v : 0.01f * v;
          else if (act == 2) v = fmaxf(v, 0.f);
          C[(size_t)m * ldc + n] = f2b(v);
        }
      }
    }
  }
}

// ---------------------------------------------------------------------------
// 2-phase 128x128 MFMA GEMM (proven R5 kernel) for small-N shapes.
template <int OUTF32>
__global__ __launch_bounds__(256) void mgemm_k(
    const u16* __restrict__ A, int lda, const u16* __restrict__ BT, int ldb,
    const float* __restrict__ bias, void* __restrict__ Cv, int ldc,
    int M, int N, int K, int accum, int act, int nbx) {
  __shared__ u16 As[2][64 * 64];
  __shared__ u16 Bs[2][64 * 64];
  const int t = threadIdx.x;
  const int w = t >> 6, l = t & 63;
  const int wr = w >> 1, wc = w & 1;
  const int fr = l & 15, hi = l >> 4;

  int nwg = gridDim.x, bid = blockIdx.x;
  int q = nwg >> 3, r = nwg & 7, xcd = bid & 7, seq = bid >> 3;
  int sid = (xcd < r ? xcd * (q + 1) : r * (q + 1) + (xcd - r) * q) + seq;
  int by = sid / nbx, bx = sid - by * nbx;
  const int row0 = by * 128, col0 = bx * 128;

  f32x4 acc[4][4];
#pragma unroll
  for (int i = 0; i < 4; i++)
#pragma unroll
    for (int jj = 0; jj < 4; jj++) acc[i][jj] = (f32x4){0.f, 0.f, 0.f, 0.f};

  const u16* Aad[2]; const u16* Bad[2];
  char* Alds[2]; char* Blds[2];
#pragma unroll
  for (int c = 0; c < 2; c++) {
    int P = (w * 2 + c) * 64 + l;
    int prow = P >> 3, s = P & 7;
    int lr = prow * 2 + (s >> 2);
    int g = (s & 3) ^ (prow & 3);
    int ar = row0 + lr; ar = ar < M ? ar : M - 1;
    int br = col0 + lr; br = br < N ? br : N - 1;
    Aad[c] = A + (size_t)ar * lda + g * 8;
    Bad[c] = BT + (size_t)br * ldb + g * 8;
    Alds[c] = (char*)&As[0][0] + P * 16;
    Blds[c] = (char*)&Bs[0][0] + P * 16;
  }
  const int nt = K >> 5;
  auto stage = [&](int tt, int b) {
    int ko = tt << 5;
#pragma unroll
    for (int c = 0; c < 2; c++) {
      gload16(Aad[c] + ko, Alds[c] + b * 8192);
      gload16(Bad[c] + ko, Blds[c] + b * 8192);
    }
  };
  auto compute = [&](int tt) {
    const u16* Ab = As[tt & 1];
    const u16* Bb = Bs[tt & 1];
    bf16x8 af[4], bfr[4];
#pragma unroll
    for (int mi = 0; mi < 4; mi++) {
      int row = wr * 64 + mi * 16 + fr;
      int pr = row >> 1;
      af[mi] = *(const bf16x8*)&Ab[pr * 64 + ((row & 1) * 4 + (hi ^ (pr & 3))) * 8];
    }
#pragma unroll
    for (int ni = 0; ni < 4; ni++) {
      int row = wc * 64 + ni * 16 + fr;
      int pr = row >> 1;
      bfr[ni] = *(const bf16x8*)&Bb[pr * 64 + ((row & 1) * 4 + (hi ^ (pr & 3))) * 8];
    }
    __builtin_amdgcn_s_setprio(1);
#pragma unroll
    for (int mi = 0; mi < 4; mi++)
#pragma unroll
      for (int ni = 0; ni < 4; ni++)
        acc[mi][ni] = __builtin_amdgcn_mfma_f32_16x16x32_bf16(
            af[mi], bfr[ni], acc[mi][ni], 0, 0, 0);
    __builtin_amdgcn_s_setprio(0);
  };

  stage(0, 0);
  if (nt > 1) stage(1, 1);
  for (int tt = 0; tt < nt - 1; tt++) {
    asm volatile("s_waitcnt vmcnt(4)" ::: "memory");
    __builtin_amdgcn_sched_barrier(0);
    __builtin_amdgcn_s_barrier();
    __builtin_amdgcn_sched_barrier(0);
    compute(tt);
    __builtin_amdgcn_sched_barrier(0);
    __builtin_amdgcn_s_barrier();
    __builtin_amdgcn_sched_barrier(0);
    if (tt + 2 < nt) stage(tt + 2, tt & 1);
  }
  asm volatile("s_waitcnt vmcnt(0)" ::: "memory");
  __builtin_amdgcn_sched_barrier(0);
  __builtin_amdgcn_s_barrier();
  __builtin_amdgcn_sched_barrier(0);
  compute(nt - 1);

#pragma unroll
  for (int mi = 0; mi < 4; mi++) {
    int mb = row0 + wr * 64 + mi * 16 + hi * 4;
#pragma unroll
    for (int rr2 = 0; rr2 < 4; rr2++) {
      int m = mb + rr2;
      if (m >= M) continue;
#pragma unroll
      for (int ni = 0; ni < 4; ni++) {
        int n = col0 + wc * 64 + ni * 16 + fr;
        if (n >= N) continue;
        float v = acc[mi][ni][rr2];
        if (bias) v += bias[n];
        if (OUTF32) {
          float* C = (float*)Cv;
          if (accum) v += C[(size_t)m * ldc + n];
          if (act == 1) v = v > 0.f ? v : 0.01f * v;
          else if (act == 2) v = fmaxf(v, 0.f);
          C[(size_t)m * ldc + n] = v;
        } else {
          u16* C = (u16*)Cv;
          if (accum) v += b2f(C[(size_t)m * ldc + n]);
          if (act == 1) v = v > 0.f ? v : 0.01f * v;
          else if (act == 2) v = fmaxf(v, 0.f);
          C[(size_t)m * ldc + n] = f2b(v);
        }
      }
    }
  }
}

// ---------------------------------------------------------------------------
// Weight convert+transpose (R11 wide version): in f32 [K,Nw] -> out bf16
// [Nw, ldb], k >= K -> 0.  64x64 tile, 4 waves; read phase: lane along n ->
// 256B/wave coalesced f32 loads; write phase: lane along k -> 128B/wave
// contiguous bf16 stores.  LDS [64][65] f32: 2-way bank aliasing only (free).
__global__ void cvtw_k(const float* __restrict__ in, int K, int Nw,
                       u16* __restrict__ out, int ldb, int Kpad) {
  __shared__ float tile[64][65];
  int k0 = blockIdx.y * 64, n0 = blockIdx.x * 64;
  int lane = threadIdx.x & 63, w = threadIdx.x >> 6;  // 4 waves
  for (int i = w; i < 64; i += 4) {
    int k = k0 + i, n = n0 + lane;
    tile[i][lane] = (k < K && n < Nw) ? in[(size_t)k * Nw + n] : 0.f;
  }
  __syncthreads();
  for (int j = w; j < 64; j += 4) {
    int n = n0 + j, k = k0 + lane;
    if (n < Nw && k < Kpad) out[(size_t)n * ldb + k] = f2b(tile[lane][j]);
  }
}

// bf16 transpose with pad: out[c*ostride + r] = (r<R) ? in[r][c] : 0, r < Rpad
__global__ void tpad_k(const u16* __restrict__ in, int R, int C, int lin,
                       u16* __restrict__ out, int ostride, int Rpad) {
  __shared__ u16 tile[32][33];
  int r0 = blockIdx.y * 32, c0 = blockIdx.x * 32;
  int tx = threadIdx.x & 31, ty = threadIdx.x >> 5;
  for (int i = ty; i < 32; i += 8)
    tile[i][tx] = (r0 + i < R && c0 + tx < C) ? in[(size_t)(r0 + i) * lin + c0 + tx] : (u16)0;
  __syncthreads();
  for (int i = ty; i < 32; i += 8) {
    int c = c0 + i, r = r0 + tx;
    if (c < C && r < Rpad) out[(size_t)c * ostride + r] = tile[tx][i];
  }
}

// f32 -> bf16 elementwise (n % 4 == 0)
__global__ void cvtx_k(const float* __restrict__ in, u16* __restrict__ out, int n) {
  int i = (blockIdx.x * 256 + threadIdx.x) * 4;
  if (i >= n) return;
  float4 v = *(const float4*)&in[i];
  uint2 o;
  o.x = (unsigned)f2b(v.x) | ((unsigned)f2b(v.y) << 16);
  o.y = (unsigned)f2b(v.z) | ((unsigned)f2b(v.w) << 16);
  *(uint2*)&out[i] = o;
}

__global__ void catbias_k(const float* b0, const float* b1, const float* b2,
                          const float* b3, int seg, float* out) {
  int i = blockIdx.x * 256 + threadIdx.x;
  if (i >= 4 * seg) return;
  const float* s = i < seg ? b0 : i < 2 * seg ? b1 : i < 3 * seg ? b2 : b3;
  out[i] = s[i & (seg - 1)];
}

// ---------------------------------------------------------------------------
// CSR build
__global__ void zero_i32(int* __restrict__ p, int n) {
  int i = blockIdx.x * 256 + threadIdx.x;
  if (i < n) p[i] = 0;
}
__global__ void count_k(const int* __restrict__ dst, int E, int* __restrict__ cnt) {
  int e = blockIdx.x * 256 + threadIdx.x;
  if (e < E) atomicAdd(&cnt[dst[e]], 1);
}
__global__ __launch_bounds__(1024) void scan_k(const int* __restrict__ cnt,
                                               int* __restrict__ rs, int N) {
  __shared__ int sd[1024];
  int t = threadIdx.x;
  int per = (N + 1023) >> 10;
  int base = t * per;
  int loc[4];
  int s = 0;
  for (int u = 0; u < per; u++) {
    int idx = base + u;
    loc[u] = s;
    int v = (idx < N) ? cnt[idx] : 0;
    s += v;
  }
  sd[t] = s;
  __syncthreads();
  for (int off = 1; off < 1024; off <<= 1) {
    int v = (t >= off) ? sd[t - off] : 0;
    __syncthreads();
    sd[t] += v;
    __syncthreads();
  }
  int prev = (t > 0) ? sd[t - 1] : 0;
  for (int u = 0; u < per; u++) {
    int idx = base + u;
    if (idx < N) rs[idx] = prev + loc[u];
  }
  if (t == 0) rs[N] = sd[1023];
}
__global__ void fill_k(const int* __restrict__ src, const int* __restrict__ dst, int E,
                       const int* __restrict__ rs, int* cursor,
                       int* __restrict__ csrc, int* __restrict__ ceid) {
  int e = blockIdx.x * 256 + threadIdx.x;
  if (e >= E) return;
  int d = dst[e];
  int p = atomicAdd(&cursor[d], 1);
  int b = rs[d] + p;
  csrc[b] = src[e];
  ceid[b] = e;
}
__global__ void dinv_k(const int* __restrict__ rs, float* __restrict__ dinv, int N) {
  int i = blockIdx.x * 256 + threadIdx.x;
  if (i < N) dinv[i] = rsqrtf((float)(rs[i + 1] - rs[i] + 1));
}

// ---------------------------------------------------------------------------
// SAGE mean aggregate, bf16 in/out, f32 accum, 8 elems/thread (whole-D; R7).
__global__ void sage_agg_k(const u16* __restrict__ X, int ld, const int* __restrict__ rs,
                           const int* __restrict__ csrc, u16* __restrict__ out, int D) {
  int i = blockIdx.y;
  int j8 = (blockIdx.x * 256 + threadIdx.x) * 8;
  if (j8 >= D) return;
  int s = rs[i], e = rs[i + 1];
  float a[8] = {0, 0, 0, 0, 0, 0, 0, 0};
  for (int p = s; p < e; p++) {
    uint4 v = *(const uint4*)&X[(size_t)csrc[p] * ld + j8];
    a[0] += b2f(v.x & 0xffff); a[1] += b2f(v.x >> 16);
    a[2] += b2f(v.y & 0xffff); a[3] += b2f(v.y >> 16);
    a[4] += b2f(v.z & 0xffff); a[5] += b2f(v.z >> 16);
    a[6] += b2f(v.w & 0xffff); a[7] += b2f(v.w >> 16);
  }
  float inv = 1.f / fmaxf((float)(e - s), 1.f);
  uint4 o;
  o.x = (unsigned)f2b(a[0] * inv) | ((unsigned)f2b(a[1] * inv) << 16);
  o.y = (unsigned)f2b(a[2] * inv) | ((unsigned)f2b(a[3] * inv) << 16);
  o.z = (unsigned)f2b(a[4] * inv) | ((unsigned)f2b(a[5] * inv) << 16);
  o.w = (unsigned)f2b(a[6] * inv) | ((unsigned)f2b(a[7] * inv) << 16);
  *(uint4*)&out[(size_t)i * ld + j8] = o;
}

// GCN aggregate + bias + leaky, bf16 in/out
__global__ void gcn_agg_k(const u16* __restrict__ HW, int ld, const int* __restrict__ rs,
                          const int* __restrict__ csrc, const float* __restrict__ dinv,
                          const float* __restrict__ bias, u16* __restrict__ out, int D) {
  int i = blockIdx.y;
  int j8 = (blockIdx.x * 256 + threadIdx.x) * 8;
  if (j8 >= D) return;
  int s = rs[i], e = rs[i + 1];
  float a[8] = {0, 0, 0, 0, 0, 0, 0, 0};
  for (int p = s; p < e; p++) {
    int sr = csrc[p];
    float w = dinv[sr];
    uint4 v = *(const uint4*)&HW[(size_t)sr * ld + j8];
    a[0] += b2f(v.x & 0xffff) * w; a[1] += b2f(v.x >> 16) * w;
    a[2] += b2f(v.y & 0xffff) * w; a[3] += b2f(v.y >> 16) * w;
    a[4] += b2f(v.z & 0xffff) * w; a[5] += b2f(v.z >> 16) * w;
    a[6] += b2f(v.w & 0xffff) * w; a[7] += b2f(v.w >> 16) * w;
  }
  float di = dinv[i];
  uint4 sv = *(const uint4*)&HW[(size_t)i * ld + j8];
  float sf[8] = {b2f(sv.x & 0xffff), b2f(sv.x >> 16), b2f(sv.y & 0xffff), b2f(sv.y >> 16),
                 b2f(sv.z & 0xffff), b2f(sv.z >> 16), b2f(sv.w & 0xffff), b2f(sv.w >> 16)};
  unsigned o[4];
#pragma unroll
  for (int qq = 0; qq < 4; qq++) {
    float v0 = di * a[2 * qq] + sf[2 * qq] * di * di + bias[j8 + 2 * qq];
    float v1 = di * a[2 * qq + 1] + sf[2 * qq + 1] * di * di + bias[j8 + 2 * qq + 1];
    v0 = v0 > 0.f ? v0 : 0.01f * v0;
    v1 = v1 > 0.f ? v1 : 0.01f * v1;
    o[qq] = (unsigned)f2b(v0) | ((unsigned)f2b(v1) << 16);
  }
  *(uint4*)&out[(size_t)i * ld + j8] = *(uint4*)o;
}

// ---------------------------------------------------------------------------
// Row transformer: per-dst softmax, d=128, QKVS concat [N,512] bf16, 1 wave/node
__global__ void attn_row_k(const u16* __restrict__ QKVS, const int* __restrict__ rs,
                           const int* __restrict__ csrc, float* __restrict__ out, int N) {
  int node = blockIdx.x * 4 + (threadIdx.x >> 6);
  if (node >= N) return;
  int lane = threadIdx.x & 63;
  const u16* base = QKVS + (size_t)node * 512;
  unsigned qb = *(const unsigned*)&base[lane * 2];
  float qx = b2f(qb & 0xffff), qy = b2f(qb >> 16);
  int s = rs[node], e = rs[node + 1];
  float m = -1e30f, z = 0.f, ax = 0.f, ay = 0.f;
  const float scale = 0.08838834764831845f;  // 1/sqrt(128)
  for (int p = s; p < e; p++) {
    const u16* kb = QKVS + (size_t)csrc[p] * 512;
    unsigned kw = *(const unsigned*)&kb[128 + lane * 2];
    float part = qx * b2f(kw & 0xffff) + qy * b2f(kw >> 16);
#pragma unroll
    for (int off = 32; off; off >>= 1) part += __shfl_xor(part, off);
    float a = part * scale;
    float mn = fmaxf(m, a);
    float sc = __expf(m - mn);
    float wv = __expf(a - mn);
    z = z * sc + wv;
    unsigned vw = *(const unsigned*)&kb[256 + lane * 2];
    ax = ax * sc + wv * b2f(vw & 0xffff);
    ay = ay * sc + wv * b2f(vw >> 16);
    m = mn;
  }
  float inv = (e == s) ? 0.f : 1.f / (z + 1e-16f);
  unsigned sw = *(const unsigned*)&base[384 + lane * 2];
  out[(size_t)node * 128 + lane * 2] = ax * inv + b2f(sw & 0xffff);
  out[(size_t)node * 128 + lane * 2 + 1] = ay * inv + b2f(sw >> 16);
}

// Col alpha: q[dst].k[src]/16, d=256, QKVS concat [N,1024] bf16, 1 wave/edge
__global__ void col_alpha_k(const u16* __restrict__ QKVS, const int* __restrict__ src,
                            const int* __restrict__ dst, float* __restrict__ alpha, int E) {
  int e = blockIdx.x * 4 + (threadIdx.x >> 6);
  if (e >= E) return;
  int lane = threadIdx.x & 63;
  uint2 qb = *(const uint2*)&QKVS[(size_t)dst[e] * 1024 + lane * 4];
  uint2 kb = *(const uint2*)&QKVS[(size_t)src[e] * 1024 + 256 + lane * 4];
  float p = b2f(qb.x & 0xffff) * b2f(kb.x & 0xffff) + b2f(qb.x >> 16) * b2f(kb.x >> 16) +
            b2f(qb.y & 0xffff) * b2f(kb.y & 0xffff) + b2f(qb.y >> 16) * b2f(kb.y >> 16);
#pragma unroll
  for (int off = 32; off; off >>= 1) p += __shfl_xor(p, off);
  if (lane == 0) alpha[e] = p * 0.0625f;
}

__global__ void stats_k(const float* __restrict__ alpha, int E, double* __restrict__ st) {
  __shared__ double s1[256], s2[256];
  int t = threadIdx.x;
  double a1 = 0, a2 = 0;
  for (int i = blockIdx.x * 256 + t; i < E; i += gridDim.x * 256) {
    double a = alpha[i];
    a1 += a; a2 += a * a;
  }
  s1[t] = a1; s2[t] = a2;
  __syncthreads();
  for (int off = 128; off; off >>= 1) {
    if (t < off) { s1[t] += s1[t + off]; s2[t] += s2[t + off]; }
    __syncthreads();
  }
  if (t == 0) { atomicAdd(&st[0], s1[0]); atomicAdd(&st[1], s2[0]); }
}

// col attention aggregate: writes f32 col_embed (d_out) and bf16 copy
__global__ void col_attn_agg_k(const u16* __restrict__ QKVS, const float* __restrict__ alpha,
                               const int* __restrict__ rs, const int* __restrict__ csrc,
                               const int* __restrict__ ceid, const double* __restrict__ st,
                               float* __restrict__ outf, u16* __restrict__ outb, int E) {
  int i = blockIdx.x;
  int j = threadIdx.x;  // 256 dims
  double mean = st[0] / E;
  double var = (st[1] - E * mean * mean) / (double)(E - 1);
  float rstd = (float)(1.0 / sqrt(var));
  float fm = (float)mean;
  int s = rs[i], e = rs[i + 1];
  float acc = 0.f;
  for (int p = s; p < e; p++) {
    float a = alpha[ceid[p]];
    float x = 3.0f * (a - fm) * rstd;
    float sg = 1.f / (1.f + __expf(-x));
    acc += sg * b2f(QKVS[(size_t)csrc[p] * 1024 + 512 + j]);
  }
  float res = acc + b2f(QKVS[(size_t)i * 1024 + 768 + j]);
  outf[(size_t)i * 256 + j] = res;
  outb[(size_t)i * 256 + j] = f2b(res);
}

// ---------------------------------------------------------------------------
extern "C" void kernel_launch(void* const* d_in, const int* in_sizes, int n_in,
                              void* d_out, int out_size, void* d_ws, size_t ws_size,
                              hipStream_t stream) {
  const float* x      = (const float*)d_in[0];
  const int*   knn_ei = (const int*)d_in[1];
  const int*   ppi_ei = (const int*)d_in[2];
  const float* rl_W   = (const float*)d_in[3];
  const float* rl_b   = (const float*)d_in[4];
  const float* rs_Wl  = (const float*)d_in[5];
  const float* rs_Wr  = (const float*)d_in[6];
  const float* rs_b   = (const float*)d_in[7];
  const float* cs_Wl  = (const float*)d_in[8];
  const float* cs_Wr  = (const float*)d_in[9];
  const float* cs_b   = (const float*)d_in[10];
  const float* rg_W   = (const float*)d_in[11];
  const float* rg_b   = (const float*)d_in[12];
  const float* rq_W   = (const float*)d_in[13];
  const float* rq_b   = (const float*)d_in[14];
  const float* rk_W   = (const float*)d_in[15];
  const float* rk_b   = (const float*)d_in[16];
  const float* rv_W   = (const float*)d_in[17];
  const float* rv_b   = (const float*)d_in[18];
  const float* rsk_W  = (const float*)d_in[19];
  const float* rsk_b  = (const float*)d_in[20];
  const float* cg_W   = (const float*)d_in[21];
  const float* cg_b   = (const float*)d_in[22];
  const float* cq_W   = (const float*)d_in[23];
  const float* cq_b   = (const float*)d_in[24];
  const float* ck_W   = (const float*)d_in[25];
  const float* ck_b   = (const float*)d_in[26];
  const float* cv_W   = (const float*)d_in[27];
  const float* cv_b   = (const float*)d_in[28];
  const float* csk_W  = (const float*)d_in[29];
  const float* csk_b  = (const float*)d_in[30];
  const float* d1_W   = (const float*)d_in[31];
  const float* d1_b   = (const float*)d_in[32];
  const float* d2_W   = (const float*)d_in[33];
  const float* d2_b   = (const float*)d_in[34];
  const float* d3_W   = (const float*)d_in[35];
  const float* d3_b   = (const float*)d_in[36];
  float* out = (float*)d_out;

  char* ws = (char*)d_ws;
  size_t off = 0;
  auto alloc = [&](size_t bytes) -> void* {
    void* p = ws + off;
    off = (off + bytes + 255) & ~(size_t)255;
    return p;
  };
  u16* P0 = (u16*)alloc((size_t)N_GENES * N_CELLS * 2);   // 24.6MB h
  u16* P1 = (u16*)alloc((size_t)N_CELLS * GPAD * 2);      // 25.2MB (CA low half)
  u16* P2 = (u16*)alloc((size_t)N_CELLS * GPAD * 2);      // 25.2MB (CA high half)
  u16* CR = (u16*)alloc((size_t)N_CELLS * 2 * GPAD * 2);  // 50.3MB xb/RA/dec
  u16* BTs = (u16*)alloc((size_t)N_CELLS * 2 * N_CELLS * 2);  // 67.1MB weights
  u16* CEb = (u16*)alloc((size_t)N_CELLS * EMBD_C * 2);
  float* catb = (float*)alloc(1024 * 4);
  int* knn_rs  = (int*)alloc((N_CELLS + 1) * 4);
  int* knn_cnt = (int*)alloc(N_CELLS * 4);
  int* knn_cur = (int*)alloc(N_CELLS * 4);
  int* knn_src = (int*)alloc(KNN_E * 4);
  int* knn_eid = (int*)alloc(KNN_E * 4);
  int* ppi_rs  = (int*)alloc((N_GENES + 1) * 4);
  int* ppi_cnt = (int*)alloc(N_GENES * 4);
  int* ppi_cur = (int*)alloc(N_GENES * 4);
  int* ppi_src = (int*)alloc(PPI_E * 4);
  int* ppi_eid = (int*)alloc(PPI_E * 4);
  float* dinv_knn = (float*)alloc(N_CELLS * 4);
  float* dinv_ppi = (float*)alloc(N_GENES * 4);
  float* alphaB   = (float*)alloc(KNN_E * 4);
  double* stats   = (double*)alloc(2 * 8);
  u16* xb = CR;   // x bf16, dead after h GEMM
  u16* RA = CR;   // row concat [3000][8192]: [ppi-mean | PcoT]
  u16* CA = P1;   // col concat [4096][6144] spans P1+P2 (contiguous allocs)

  auto cvtw = [&](const float* W, int K, int Nw, u16* dst, int ldb, int Kpad) {
    dim3 g((Nw + 63) / 64, (Kpad + 63) / 64);
    cvtw_k<<<g, 256, 0, stream>>>(W, K, Nw, dst, ldb, Kpad);
  };
  auto mg = [&](const u16* A, int lda, const u16* BT, int ldb, const float* bias,
                void* C, int ldc, int M, int N, int K, int accum, int act, int outf32) {
    int nbx = (N + 127) / 128, nby = (M + 127) / 128;
    dim3 g(nbx * nby);
    if (outf32)
      mgemm_k<1><<<g, 256, 0, stream>>>(A, lda, BT, ldb, bias, C, ldc, M, N, K, accum, act, nbx);
    else
      mgemm_k<0><<<g, 256, 0, stream>>>(A, lda, BT, ldb, bias, C, ldc, M, N, K, accum, act, nbx);
  };
  // big GEMMs: 192x256 tile (MF=6) -> 16x16 = 256 blocks for M=3000, N=4096
  auto mg8 = [&](const u16* A, int lda, const u16* BT, int ldb, const float* bias,
                 int biasRow, void* C, int ldc, int M, int N, int K, int act, int outf32) {
    int nbx = (N + 255) / 256, nby = (M + 191) / 192;
    dim3 g(nbx * nby);
    if (outf32)
      mgemm8_k<1, 6><<<g, 512, 0, stream>>>(A, lda, BT, ldb, bias, biasRow, C, ldc,
                                            M, N, K, 0, act, nbx);
    else
      mgemm8_k<0, 6><<<g, 512, 0, stream>>>(A, lda, BT, ldb, bias, biasRow, C, ldc,
                                            M, N, K, 0, act, nbx);
  };
  auto tpad = [&](const u16* in, int R, int C, int lin, u16* o, int ostride, int Rpad) {
    dim3 g((C + 31) / 32, (Rpad + 31) / 32);
    tpad_k<<<g, 256, 0, stream>>>(in, R, C, lin, o, ostride, Rpad);
  };
  auto sage = [&](const u16* X, int ld, const int* rs, const int* csrc, u16* o,
                  int nodes, int D) {
    dim3 g((D / 8 + 255) / 256, nodes);
    sage_agg_k<<<g, 256, 0, stream>>>(X, ld, rs, csrc, o, D);
  };
  auto gcn = [&](const u16* HW, int ld, const int* rs, const int* csrc, const float* dinv,
                 const float* bias, u16* o, int nodes, int D) {
    dim3 g((D / 8 + 255) / 256, nodes);
    gcn_agg_k<<<g, 256, 0, stream>>>(HW, ld, rs, csrc, dinv, bias, o, D);
  };

  // ---- CSR build ----
  zero_i32<<<(N_CELLS + 255) / 256, 256, 0, stream>>>(knn_cnt, N_CELLS);
  count_k<<<(KNN_E + 255) / 256, 256, 0, stream>>>(knn_ei + KNN_E, KNN_E, knn_cnt);
  scan_k<<<1, 1024, 0, stream>>>(knn_cnt, knn_rs, N_CELLS);
  zero_i32<<<(N_CELLS + 255) / 256, 256, 0, stream>>>(knn_cur, N_CELLS);
  fill_k<<<(KNN_E + 255) / 256, 256, 0, stream>>>(knn_ei, knn_ei + KNN_E, KNN_E,
                                                  knn_rs, knn_cur, knn_src, knn_eid);
  dinv_k<<<(N_CELLS + 255) / 256, 256, 0, stream>>>(knn_rs, dinv_knn, N_CELLS);
  zero_i32<<<(N_GENES + 255) / 256, 256, 0, stream>>>(ppi_cnt, N_GENES);
  count_k<<<(PPI_E + 255) / 256, 256, 0, stream>>>(ppi_ei + PPI_E, PPI_E, ppi_cnt);
  scan_k<<<1, 1024, 0, stream>>>(ppi_cnt, ppi_rs, N_GENES);
  zero_i32<<<(N_GENES + 255) / 256, 256, 0, stream>>>(ppi_cur, N_GENES);
  fill_k<<<(PPI_E + 255) / 256, 256, 0, stream>>>(ppi_ei, ppi_ei + PPI_E, PPI_E,
                                                  ppi_rs, ppi_cur, ppi_src, ppi_eid);
  dinv_k<<<(N_GENES + 255) / 256, 256, 0, stream>>>(ppi_rs, dinv_ppi, N_GENES);

  // ---- x -> bf16; h = x @ rl_W + rl_b  [3000,4096] -> P0 ----
  cvtx_k<<<(N_GENES * N_CELLS / 4 + 255) / 256, 256, 0, stream>>>(
      x, xb, N_GENES * N_CELLS);
  cvtw(rl_W, N_CELLS, N_CELLS, BTs, N_CELLS, N_CELLS);
  mg8(xb, N_CELLS, BTs, N_CELLS, rl_b, 0, P0, N_CELLS, N_GENES, N_CELLS, N_CELLS, 0, 0);

  // ---- 2 mutual SAGE layers, Wl/Wr fused via K-concat ----
  for (int i = 0; i < 2; i++) {
    const float* cWl = cs_Wl + (size_t)i * N_GENES * N_GENES;
    const float* cWr = cs_Wr + (size_t)i * N_GENES * N_GENES;
    const float* cb  = cs_b + (size_t)i * N_GENES;
    const float* rWl = rs_Wl + (size_t)i * N_CELLS * N_CELLS;
    const float* rWr = rs_Wr + (size_t)i * N_CELLS * N_CELLS;
    const float* rb  = rs_b + (size_t)i * N_CELLS;
    // CA = [knn-mean(hT) | hT]  [4096][6144] in P1+P2
    tpad(P0, N_GENES, N_CELLS, N_CELLS, CA + GPAD, 2 * GPAD, GPAD);
    sage(CA + GPAD, 2 * GPAD, knn_rs, knn_src, CA, N_CELLS, GPAD);
    cvtw(cWl, N_GENES, N_GENES, BTs, 2 * GPAD, GPAD);
    cvtw(cWr, N_GENES, N_GENES, BTs + GPAD, 2 * GPAD, GPAD);
    // PcoT = leaky(Wcat @ CA^T + cb[row])  [3000][4096] into RA's PcoT slot
    mg8(BTs, 2 * GPAD, CA, 2 * GPAD, cb, 1, RA + N_CELLS, 2 * N_CELLS,
        N_GENES, N_CELLS, 2 * GPAD, 1, 0);
    // RA = [ppi-mean(PcoT) | PcoT]  [3000][8192]
    sage(RA + N_CELLS, 2 * N_CELLS, ppi_rs, ppi_src, RA, N_GENES, N_CELLS);
    cvtw(rWl, N_CELLS, N_CELLS, BTs, 2 * N_CELLS, N_CELLS);
    cvtw(rWr, N_CELLS, N_CELLS, BTs + N_CELLS, 2 * N_CELLS, N_CELLS);
    // h = leaky(RA @ [rWl;rWr]^T + rb)  [3000][4096] -> P0
    mg8(RA, 2 * N_CELLS, BTs, 2 * N_CELLS, rb, 0, P0, N_CELLS,
        N_GENES, N_CELLS, 2 * N_CELLS, 1, 0);
  }

  // ---- row (gene) encoder ----
  cvtw(rg_W, N_CELLS, INTER_R, BTs, N_CELLS, N_CELLS);
  mg(P0, N_CELLS, BTs, N_CELLS, nullptr, P1, INTER_R, N_GENES, INTER_R, N_CELLS, 0, 0, 0);
  gcn(P1, INTER_R, ppi_rs, ppi_src, dinv_ppi, rg_b, P2, N_GENES, INTER_R);
  cvtw(rq_W, INTER_R, EMBD_R, BTs + (size_t)0 * EMBD_R * INTER_R, INTER_R, INTER_R);
  cvtw(rk_W, INTER_R, EMBD_R, BTs + (size_t)1 * EMBD_R * INTER_R, INTER_R, INTER_R);
  cvtw(rv_W, INTER_R, EMBD_R, BTs + (size_t)2 * EMBD_R * INTER_R, INTER_R, INTER_R);
  cvtw(rsk_W, INTER_R, EMBD_R, BTs + (size_t)3 * EMBD_R * INTER_R, INTER_R, INTER_R);
  catbias_k<<<2, 256, 0, stream>>>(rq_b, rk_b, rv_b, rsk_b, EMBD_R, catb);
  mg(P2, INTER_R, BTs, INTER_R, catb, P1, 4 * EMBD_R, N_GENES, 4 * EMBD_R, INTER_R, 0, 0, 0);
  attn_row_k<<<(N_GENES + 3) / 4, 256, 0, stream>>>(P1, ppi_rs, ppi_src, out, N_GENES);

  // ---- col (cell) encoder ----
  tpad(P0, N_GENES, N_CELLS, N_CELLS, P1, GPAD, GPAD);             // hT [4096,3072p]
  cvtw(cg_W, N_GENES, INTER_C, BTs, GPAD, GPAD);
  mg(P1, GPAD, BTs, GPAD, nullptr, P2, INTER_C, N_CELLS, INTER_C, GPAD, 0, 0, 0);
  gcn(P2, INTER_C, knn_rs, knn_src, dinv_knn, cg_b, P0, N_CELLS, INTER_C);
  cvtw(cq_W, INTER_C, EMBD_C, BTs + (size_t)0 * EMBD_C * INTER_C, INTER_C, INTER_C);
  cvtw(ck_W, INTER_C, EMBD_C, BTs + (size_t)1 * EMBD_C * INTER_C, INTER_C, INTER_C);
  cvtw(cv_W, INTER_C, EMBD_C, BTs + (size_t)2 * EMBD_C * INTER_C, INTER_C, INTER_C);
  cvtw(csk_W, INTER_C, EMBD_C, BTs + (size_t)3 * EMBD_C * INTER_C, INTER_C, INTER_C);
  catbias_k<<<4, 256, 0, stream>>>(cq_b, ck_b, cv_b, csk_b, EMBD_C, catb);
  mg(P0, INTER_C, BTs, INTER_C, catb, P1, 4 * EMBD_C, N_CELLS, 4 * EMBD_C, INTER_C, 0, 0, 0);
  col_alpha_k<<<KNN_E / 4, 256, 0, stream>>>(P1, knn_ei, knn_ei + KNN_E, alphaB, KNN_E);
  zero_i32<<<1, 256, 0, stream>>>((int*)stats, 4);
  stats_k<<<64, 256, 0, stream>>>(alphaB, KNN_E, stats);
  float* col_embed = out + (size_t)N_GENES * EMBD_R;
  col_attn_agg_k<<<N_CELLS, 256, 0, stream>>>(P1, alphaB, knn_rs, knn_src, knn_eid,
                                              stats, col_embed, CEb, KNN_E);

  // ---- decoder (temps in CR, free after SAGE loop) ----
  u16* D1 = CR;
  u16* D2 = CR + (size_t)N_CELLS * INTER_C;
  float* recon = col_embed + (size_t)N_CELLS * EMBD_C;
  cvtw(d1_W, EMBD_C, INTER_C, BTs, EMBD_C, EMBD_C);
  mg(CEb, EMBD_C, BTs, EMBD_C, d1_b, D1, INTER_C, N_CELLS, INTER_C, EMBD_C, 0, 2, 0);
  cvtw(d2_W, INTER_C, INTER_C, BTs, INTER_C, INTER_C);
  mg(D1, INTER_C, BTs, INTER_C, d2_b, D2, INTER_C, N_CELLS, INTER_C, INTER_C, 0, 2, 0);
  cvtw(d3_W, INTER_C, N_GENES, BTs, INTER_C, INTER_C);
  mg(D2, INTER_C, BTs, INTER_C, d3_b, recon, N_GENES, N_CELLS, N_GENES, INTER_C, 0, 0, 1);
}

// Round 12
// 2253.742 us; speedup vs baseline: 1.0310x; 1.0310x over previous
//
#include <hip/hip_runtime.h>
#include <math.h>

#define N_GENES 3000
#define N_CELLS 4096
#define GPAD    3072
#define INTER_R 512
#define EMBD_R  128
#define INTER_C 1024
#define EMBD_C  256
#define KNN_E   65536
#define PPI_E   262144

typedef unsigned short u16;
typedef __bf16 bf16x8 __attribute__((ext_vector_type(8)));
typedef float f32x4 __attribute__((ext_vector_type(4)));

__device__ __forceinline__ float b2f(u16 u) {
  union { unsigned i; float f; } x; x.i = ((unsigned)u) << 16; return x.f;
}
__device__ __forceinline__ u16 f2b(float f) {
  union { float f; unsigned i; } x; x.f = f;
  unsigned r = (x.i + 0x7FFFu + ((x.i >> 16) & 1u)) >> 16;
  return (u16)r;
}

typedef const void __attribute__((address_space(1))) gvoid;
typedef void __attribute__((address_space(3))) svoid;
__device__ __forceinline__ void gload16(const void* g, void* l) {
  __builtin_amdgcn_global_load_lds((gvoid*)g, (svoid*)l, 16, 0, 0);
}

// ---------------------------------------------------------------------------
// 8-phase MFMA bf16 GEMM, tile TM x 256 where TM = MF*32 (MF=6: 192).
// C[M,N] = act((accum?C:0) + A[M,K]@BT[N,K]^T + (biasRow?bias[m]:bias[n])).
// K % 64 == 0, K/64 >= 3.  512 thr = 8 waves (2M x 4N), wave = (MF*16) x 64.
// R7-proven config (measured best, 2256us total): 192x256 tiles -> 16x16 =
// 256 blocks for M=3000, N=4096 (exactly 1 block/CU on all 256 CUs).
// LDS 112KB.  Region layout [rows][4 slots x 16B], slot = khi ^ ((row>>1)&3)
// (measured-0-conflict).  Counted vmcnt once per K-tile (waves 0-3: 6,
// waves 4-7: 4 -- one fewer A chunk); raw barriers; setprio around MFMA.
template <int OUTF32, int MF>
__global__ __launch_bounds__(512, 1) void mgemm8_k(
    const u16* __restrict__ A, int lda, const u16* __restrict__ BT, int ldb,
    const float* __restrict__ bias, int biasRow, void* __restrict__ Cv, int ldc,
    int M, int N, int K, int accum, int act, int nbx) {
  constexpr int MFH = MF / 2;
  constexpr int TM = MF * 32;
  constexpr int ABYTES = TM * 64;
  constexpr int BBYTES = 16384;
  constexpr int BUFB = 2 * ABYTES + 2 * BBYTES;
  __shared__ char S[2 * BUFB];
  const int t = threadIdx.x;
  const int wid = t >> 6;
  const int l = t & 63;
  const int wm = wid >> 2, wn = wid & 3;
  const int fr = l & 15, hi = l >> 4;

  // bijective XCD swizzle (m204)
  int nwg = gridDim.x, bid = blockIdx.x;
  int q = nwg >> 3, r = nwg & 7, xcd = bid & 7, seq = bid >> 3;
  int sid = (xcd < r ? xcd * (q + 1) : r * (q + 1) + (xcd - r) * q) + seq;
  int by = sid / nbx, bx = sid - by * nbx;
  const int row0 = by * TM, col0 = bx * 256;

  f32x4 acc[MF][4];
#pragma unroll
  for (int i = 0; i < MF; i++)
#pragma unroll
    for (int jj = 0; jj < 4; jj++) acc[i][jj] = (f32x4){0.f, 0.f, 0.f, 0.f};

  // staging chunk mapping: chunk c -> row=c>>2, slot=c&3, logical g=slot^((row>>1)&3)
  const int cA1 = t, cA2 = t + 512;
  const int rA1 = cA1 >> 2, rA2 = cA2 >> 2;
  const int gA1 = (cA1 & 3) ^ ((rA1 >> 1) & 3);
  const int gA2 = (cA2 & 3) ^ ((rA2 >> 1) & 3);
  int arow1 = row0 + rA1; arow1 = arow1 < M ? arow1 : M - 1;
  int arow2 = row0 + (rA2 < TM ? rA2 : TM - 1); arow2 = arow2 < M ? arow2 : M - 1;
  const u16* baseA1 = A + (size_t)arow1 * lda + gA1 * 8;
  const u16* baseA2 = A + (size_t)arow2 * lda + gA2 * 8;
  const bool doA2 = (MF == 8) || (t < 256);
  int brow1 = col0 + rA1; brow1 = brow1 < N ? brow1 : N - 1;
  int brow2 = col0 + rA2; brow2 = brow2 < N ? brow2 : N - 1;
  const u16* baseB1 = BT + (size_t)brow1 * ldb + gA1 * 8;
  const u16* baseB2 = BT + (size_t)brow2 * ldb + gA2 * 8;

  auto aoff = [](int buf, int kh) { return buf * BUFB + kh * ABYTES; };
  auto boff = [](int buf, int kh) { return buf * BUFB + 2 * ABYTES + kh * BBYTES; };

  auto stageA = [&](int buf, int kh, int kt) {
    int ko = kt * 64 + kh * 32;
    gload16(baseA1 + ko, S + aoff(buf, kh) + cA1 * 16);
    if (doA2) gload16(baseA2 + ko, S + aoff(buf, kh) + cA2 * 16);
  };
  auto stageB = [&](int buf, int kh, int kt) {
    int ko = kt * 64 + kh * 32;
    gload16(baseB1 + ko, S + boff(buf, kh) + cA1 * 16);
    gload16(baseB2 + ko, S + boff(buf, kh) + cA2 * 16);
  };

  bf16x8 af[MFH], bfr[4];
  auto dsrA = [&](int buf, int kh, int mh) {
#pragma unroll
    for (int i = 0; i < MFH; i++) {
      int row = wm * (MF * 16) + (mh * MFH + i) * 16 + fr;
      af[i] = *(const bf16x8*)(S + aoff(buf, kh) + row * 64 +
                               ((hi ^ ((row >> 1) & 3)) << 4));
    }
  };
  auto dsrB = [&](int buf, int kh) {
#pragma unroll
    for (int i = 0; i < 4; i++) {
      int row = wn * 64 + i * 16 + fr;
      bfr[i] = *(const bf16x8*)(S + boff(buf, kh) + row * 64 +
                                ((hi ^ ((row >> 1) & 3)) << 4));
    }
  };
  auto mma = [&](int mh) {
    __builtin_amdgcn_s_setprio(1);
#pragma unroll
    for (int i = 0; i < MFH; i++)
#pragma unroll
      for (int jj = 0; jj < 4; jj++)
        acc[mh * MFH + i][jj] = __builtin_amdgcn_mfma_f32_16x16x32_bf16(
            af[i], bfr[jj], acc[mh * MFH + i][jj], 0, 0, 0);
    __builtin_amdgcn_s_setprio(0);
  };
  auto vmw = [&]() {
    if (MF == 6 && wid >= 4)
      asm volatile("s_waitcnt vmcnt(4)" ::: "memory");
    else
      asm volatile("s_waitcnt vmcnt(6)" ::: "memory");
  };
  auto barmid = [&]() {
    __builtin_amdgcn_sched_barrier(0);
    __builtin_amdgcn_s_barrier();
    asm volatile("s_waitcnt lgkmcnt(0)" ::: "memory");
    __builtin_amdgcn_sched_barrier(0);
  };
  auto barend = [&]() {
    __builtin_amdgcn_sched_barrier(0);
    __builtin_amdgcn_s_barrier();
    __builtin_amdgcn_sched_barrier(0);
  };

  const int nt = K >> 6;
  // prologue: tile0 full + tile1 {A0,B0,A1}
  stageA(0, 0, 0); stageB(0, 0, 0); stageA(0, 1, 0); stageB(0, 1, 0);
  stageA(1, 0, 1); stageB(1, 0, 1); stageA(1, 1, 1);
  vmw();
  __builtin_amdgcn_sched_barrier(0);
  __builtin_amdgcn_s_barrier();
  __builtin_amdgcn_sched_barrier(0);

  int p = 0;
  for (int kt = 0; kt < nt - 2; kt++, p ^= 1) {
    dsrA(p, 0, 0); dsrB(p, 0);
    stageB(p ^ 1, 1, kt + 1);
    barmid(); mma(0); barend();
    dsrA(p, 0, 1);
    stageA(p, 0, kt + 2);
    barmid(); mma(1); barend();
    dsrA(p, 1, 0); dsrB(p, 1);
    stageB(p, 0, kt + 2);
    barmid(); mma(0); barend();
    dsrA(p, 1, 1);
    stageA(p, 1, kt + 2);
    vmw();
    barmid(); mma(1); barend();
  }
  // peeled kt = nt-2
  dsrA(p, 0, 0); dsrB(p, 0);
  stageB(p ^ 1, 1, nt - 1);
  barmid(); mma(0); barend();
  dsrA(p, 0, 1);
  barmid(); mma(1); barend();
  dsrA(p, 1, 0); dsrB(p, 1);
  barmid(); mma(0); barend();
  dsrA(p, 1, 1);
  asm volatile("s_waitcnt vmcnt(0)" ::: "memory");
  barmid(); mma(1); barend();
  p ^= 1;
  // peeled kt = nt-1
  dsrA(p, 0, 0); dsrB(p, 0);
  barmid(); mma(0); barend();
  dsrA(p, 0, 1);
  barmid(); mma(1); barend();
  dsrA(p, 1, 0); dsrB(p, 1);
  barmid(); mma(0); barend();
  dsrA(p, 1, 1);
  barmid(); mma(1); barend();

#pragma unroll
  for (int mf = 0; mf < MF; mf++) {
    int mb = row0 + wm * (MF * 16) + mf * 16 + hi * 4;
#pragma unroll
    for (int rr2 = 0; rr2 < 4; rr2++) {
      int m = mb + rr2;
      if (m >= M) continue;
#pragma unroll
      for (int nf = 0; nf < 4; nf++) {
        int n = col0 + wn * 64 + nf * 16 + fr;
        if (n >= N) continue;
        float v = acc[mf][nf][rr2];
        if (bias) v += biasRow ? bias[m] : bias[n];
        if (OUTF32) {
          float* C = (float*)Cv;
          if (accum) v += C[(size_t)m * ldc + n];
          if (act == 1) v = v > 0.f ? v : 0.01f * v;
          else if (act == 2) v = fmaxf(v, 0.f);
          C[(size_t)m * ldc + n] = v;
        } else {
          u16* C = (u16*)Cv;
          if (accum) v += b2f(C[(size_t)m * ldc + n]);
          if (act == 1) v = v > 0.f ? v : 0.01f * v;
          else if (act == 2) v = fmaxf(v, 0.f);
          C[(size_t)m * ldc + n] = f2b(v);
        }
      }
    }
  }
}

// ---------------------------------------------------------------------------
// 2-phase 128x128 MFMA GEMM (proven R5 kernel) for small-N shapes.
template <int OUTF32>
__global__ __launch_bounds__(256) void mgemm_k(
    const u16* __restrict__ A, int lda, const u16* __restrict__ BT, int ldb,
    const float* __restrict__ bias, void* __restrict__ Cv, int ldc,
    int M, int N, int K, int accum, int act, int nbx) {
  __shared__ u16 As[2][64 * 64];
  __shared__ u16 Bs[2][64 * 64];
  const int t = threadIdx.x;
  const int w = t >> 6, l = t & 63;
  const int wr = w >> 1, wc = w & 1;
  const int fr = l & 15, hi = l >> 4;

  int nwg = gridDim.x, bid = blockIdx.x;
  int q = nwg >> 3, r = nwg & 7, xcd = bid & 7, seq = bid >> 3;
  int sid = (xcd < r ? xcd * (q + 1) : r * (q + 1) + (xcd - r) * q) + seq;
  int by = sid / nbx, bx = sid - by * nbx;
  const int row0 = by * 128, col0 = bx * 128;

  f32x4 acc[4][4];
#pragma unroll
  for (int i = 0; i < 4; i++)
#pragma unroll
    for (int jj = 0; jj < 4; jj++) acc[i][jj] = (f32x4){0.f, 0.f, 0.f, 0.f};

  const u16* Aad[2]; const u16* Bad[2];
  char* Alds[2]; char* Blds[2];
#pragma unroll
  for (int c = 0; c < 2; c++) {
    int P = (w * 2 + c) * 64 + l;
    int prow = P >> 3, s = P & 7;
    int lr = prow * 2 + (s >> 2);
    int g = (s & 3) ^ (prow & 3);
    int ar = row0 + lr; ar = ar < M ? ar : M - 1;
    int br = col0 + lr; br = br < N ? br : N - 1;
    Aad[c] = A + (size_t)ar * lda + g * 8;
    Bad[c] = BT + (size_t)br * ldb + g * 8;
    Alds[c] = (char*)&As[0][0] + P * 16;
    Blds[c] = (char*)&Bs[0][0] + P * 16;
  }
  const int nt = K >> 5;
  auto stage = [&](int tt, int b) {
    int ko = tt << 5;
#pragma unroll
    for (int c = 0; c < 2; c++) {
      gload16(Aad[c] + ko, Alds[c] + b * 8192);
      gload16(Bad[c] + ko, Blds[c] + b * 8192);
    }
  };
  auto compute = [&](int tt) {
    const u16* Ab = As[tt & 1];
    const u16* Bb = Bs[tt & 1];
    bf16x8 af[4], bfr[4];
#pragma unroll
    for (int mi = 0; mi < 4; mi++) {
      int row = wr * 64 + mi * 16 + fr;
      int pr = row >> 1;
      af[mi] = *(const bf16x8*)&Ab[pr * 64 + ((row & 1) * 4 + (hi ^ (pr & 3))) * 8];
    }
#pragma unroll
    for (int ni = 0; ni < 4; ni++) {
      int row = wc * 64 + ni * 16 + fr;
      int pr = row >> 1;
      bfr[ni] = *(const bf16x8*)&Bb[pr * 64 + ((row & 1) * 4 + (hi ^ (pr & 3))) * 8];
    }
    __builtin_amdgcn_s_setprio(1);
#pragma unroll
    for (int mi = 0; mi < 4; mi++)
#pragma unroll
      for (int ni = 0; ni < 4; ni++)
        acc[mi][ni] = __builtin_amdgcn_mfma_f32_16x16x32_bf16(
            af[mi], bfr[ni], acc[mi][ni], 0, 0, 0);
    __builtin_amdgcn_s_setprio(0);
  };

  stage(0, 0);
  if (nt > 1) stage(1, 1);
  for (int tt = 0; tt < nt - 1; tt++) {
    asm volatile("s_waitcnt vmcnt(4)" ::: "memory");
    __builtin_amdgcn_sched_barrier(0);
    __builtin_amdgcn_s_barrier();
    __builtin_amdgcn_sched_barrier(0);
    compute(tt);
    __builtin_amdgcn_sched_barrier(0);
    __builtin_amdgcn_s_barrier();
    __builtin_amdgcn_sched_barrier(0);
    if (tt + 2 < nt) stage(tt + 2, tt & 1);
  }
  asm volatile("s_waitcnt vmcnt(0)" ::: "memory");
  __builtin_amdgcn_sched_barrier(0);
  __builtin_amdgcn_s_barrier();
  __builtin_amdgcn_sched_barrier(0);
  compute(nt - 1);

#pragma unroll
  for (int mi = 0; mi < 4; mi++) {
    int mb = row0 + wr * 64 + mi * 16 + hi * 4;
#pragma unroll
    for (int rr2 = 0; rr2 < 4; rr2++) {
      int m = mb + rr2;
      if (m >= M) continue;
#pragma unroll
      for (int ni = 0; ni < 4; ni++) {
        int n = col0 + wc * 64 + ni * 16 + fr;
        if (n >= N) continue;
        float v = acc[mi][ni][rr2];
        if (bias) v += bias[n];
        if (OUTF32) {
          float* C = (float*)Cv;
          if (accum) v += C[(size_t)m * ldc + n];
          if (act == 1) v = v > 0.f ? v : 0.01f * v;
          else if (act == 2) v = fmaxf(v, 0.f);
          C[(size_t)m * ldc + n] = v;
        } else {
          u16* C = (u16*)Cv;
          if (accum) v += b2f(C[(size_t)m * ldc + n]);
          if (act == 1) v = v > 0.f ? v : 0.01f * v;
          else if (act == 2) v = fmaxf(v, 0.f);
          C[(size_t)m * ldc + n] = f2b(v);
        }
      }
    }
  }
}

// ---------------------------------------------------------------------------
// Weight convert+transpose: in f32 [K,Nw] -> out bf16 [Nw, ldb], k >= K -> 0
// (R7-proven 32x32 version; R11's 64x64 "wide" variant measured slower.)
__global__ void cvtw_k(const float* __restrict__ in, int K, int Nw,
                       u16* __restrict__ out, int ldb, int Kpad) {
  __shared__ float tile[32][33];
  int k0 = blockIdx.y * 32, n0 = blockIdx.x * 32;
  int tx = threadIdx.x & 31, ty = threadIdx.x >> 5;
  for (int i = ty; i < 32; i += 8)
    tile[i][tx] = (k0 + i < K && n0 + tx < Nw) ? in[(size_t)(k0 + i) * Nw + n0 + tx] : 0.f;
  __syncthreads();
  for (int i = ty; i < 32; i += 8) {
    int n = n0 + i, k = k0 + tx;
    if (n < Nw && k < Kpad) out[(size_t)n * ldb + k] = f2b(tile[tx][i]);
  }
}

// bf16 transpose with pad: out[c*ostride + r] = (r<R) ? in[r][c] : 0, r < Rpad
__global__ void tpad_k(const u16* __restrict__ in, int R, int C, int lin,
                       u16* __restrict__ out, int ostride, int Rpad) {
  __shared__ u16 tile[32][33];
  int r0 = blockIdx.y * 32, c0 = blockIdx.x * 32;
  int tx = threadIdx.x & 31, ty = threadIdx.x >> 5;
  for (int i = ty; i < 32; i += 8)
    tile[i][tx] = (r0 + i < R && c0 + tx < C) ? in[(size_t)(r0 + i) * lin + c0 + tx] : (u16)0;
  __syncthreads();
  for (int i = ty; i < 32; i += 8) {
    int c = c0 + i, r = r0 + tx;
    if (c < C && r < Rpad) out[(size_t)c * ostride + r] = tile[tx][i];
  }
}

// f32 -> bf16 elementwise (n % 4 == 0)
__global__ void cvtx_k(const float* __restrict__ in, u16* __restrict__ out, int n) {
  int i = (blockIdx.x * 256 + threadIdx.x) * 4;
  if (i >= n) return;
  float4 v = *(const float4*)&in[i];
  uint2 o;
  o.x = (unsigned)f2b(v.x) | ((unsigned)f2b(v.y) << 16);
  o.y = (unsigned)f2b(v.z) | ((unsigned)f2b(v.w) << 16);
  *(uint2*)&out[i] = o;
}

__global__ void catbias_k(const float* b0, const float* b1, const float* b2,
                          const float* b3, int seg, float* out) {
  int i = blockIdx.x * 256 + threadIdx.x;
  if (i >= 4 * seg) return;
  const float* s = i < seg ? b0 : i < 2 * seg ? b1 : i < 3 * seg ? b2 : b3;
  out[i] = s[i & (seg - 1)];
}

// ---------------------------------------------------------------------------
// CSR build
__global__ void zero_i32(int* __restrict__ p, int n) {
  int i = blockIdx.x * 256 + threadIdx.x;
  if (i < n) p[i] = 0;
}
__global__ void count_k(const int* __restrict__ dst, int E, int* __restrict__ cnt) {
  int e = blockIdx.x * 256 + threadIdx.x;
  if (e < E) atomicAdd(&cnt[dst[e]], 1);
}
__global__ __launch_bounds__(1024) void scan_k(const int* __restrict__ cnt,
                                               int* __restrict__ rs, int N) {
  __shared__ int sd[1024];
  int t = threadIdx.x;
  int per = (N + 1023) >> 10;
  int base = t * per;
  int loc[4];
  int s = 0;
  for (int u = 0; u < per; u++) {
    int idx = base + u;
    loc[u] = s;
    int v = (idx < N) ? cnt[idx] : 0;
    s += v;
  }
  sd[t] = s;
  __syncthreads();
  for (int off = 1; off < 1024; off <<= 1) {
    int v = (t >= off) ? sd[t - off] : 0;
    __syncthreads();
    sd[t] += v;
    __syncthreads();
  }
  int prev = (t > 0) ? sd[t - 1] : 0;
  for (int u = 0; u < per; u++) {
    int idx = base + u;
    if (idx < N) rs[idx] = prev + loc[u];
  }
  if (t == 0) rs[N] = sd[1023];
}
__global__ void fill_k(const int* __restrict__ src, const int* __restrict__ dst, int E,
                       const int* __restrict__ rs, int* cursor,
                       int* __restrict__ csrc, int* __restrict__ ceid) {
  int e = blockIdx.x * 256 + threadIdx.x;
  if (e >= E) return;
  int d = dst[e];
  int p = atomicAdd(&cursor[d], 1);
  int b = rs[d] + p;
  csrc[b] = src[e];
  ceid[b] = e;
}
__global__ void dinv_k(const int* __restrict__ rs, float* __restrict__ dinv, int N) {
  int i = blockIdx.x * 256 + threadIdx.x;
  if (i < N) dinv[i] = rsqrtf((float)(rs[i + 1] - rs[i] + 1));
}

// ---------------------------------------------------------------------------
// SAGE mean aggregate, bf16 in/out, f32 accum, 8 elems/thread (whole-D; R7).
__global__ void sage_agg_k(const u16* __restrict__ X, int ld, const int* __restrict__ rs,
                           const int* __restrict__ csrc, u16* __restrict__ out, int D) {
  int i = blockIdx.y;
  int j8 = (blockIdx.x * 256 + threadIdx.x) * 8;
  if (j8 >= D) return;
  int s = rs[i], e = rs[i + 1];
  float a[8] = {0, 0, 0, 0, 0, 0, 0, 0};
  for (int p = s; p < e; p++) {
    uint4 v = *(const uint4*)&X[(size_t)csrc[p] * ld + j8];
    a[0] += b2f(v.x & 0xffff); a[1] += b2f(v.x >> 16);
    a[2] += b2f(v.y & 0xffff); a[3] += b2f(v.y >> 16);
    a[4] += b2f(v.z & 0xffff); a[5] += b2f(v.z >> 16);
    a[6] += b2f(v.w & 0xffff); a[7] += b2f(v.w >> 16);
  }
  float inv = 1.f / fmaxf((float)(e - s), 1.f);
  uint4 o;
  o.x = (unsigned)f2b(a[0] * inv) | ((unsigned)f2b(a[1] * inv) << 16);
  o.y = (unsigned)f2b(a[2] * inv) | ((unsigned)f2b(a[3] * inv) << 16);
  o.z = (unsigned)f2b(a[4] * inv) | ((unsigned)f2b(a[5] * inv) << 16);
  o.w = (unsigned)f2b(a[6] * inv) | ((unsigned)f2b(a[7] * inv) << 16);
  *(uint4*)&out[(size_t)i * ld + j8] = o;
}

// GCN aggregate + bias + leaky, bf16 in/out
__global__ void gcn_agg_k(const u16* __restrict__ HW, int ld, const int* __restrict__ rs,
                          const int* __restrict__ csrc, const float* __restrict__ dinv,
                          const float* __restrict__ bias, u16* __restrict__ out, int D) {
  int i = blockIdx.y;
  int j8 = (blockIdx.x * 256 + threadIdx.x) * 8;
  if (j8 >= D) return;
  int s = rs[i], e = rs[i + 1];
  float a[8] = {0, 0, 0, 0, 0, 0, 0, 0};
  for (int p = s; p < e; p++) {
    int sr = csrc[p];
    float w = dinv[sr];
    uint4 v = *(const uint4*)&HW[(size_t)sr * ld + j8];
    a[0] += b2f(v.x & 0xffff) * w; a[1] += b2f(v.x >> 16) * w;
    a[2] += b2f(v.y & 0xffff) * w; a[3] += b2f(v.y >> 16) * w;
    a[4] += b2f(v.z & 0xffff) * w; a[5] += b2f(v.z >> 16) * w;
    a[6] += b2f(v.w & 0xffff) * w; a[7] += b2f(v.w >> 16) * w;
  }
  float di = dinv[i];
  uint4 sv = *(const uint4*)&HW[(size_t)i * ld + j8];
  float sf[8] = {b2f(sv.x & 0xffff), b2f(sv.x >> 16), b2f(sv.y & 0xffff), b2f(sv.y >> 16),
                 b2f(sv.z & 0xffff), b2f(sv.z >> 16), b2f(sv.w & 0xffff), b2f(sv.w >> 16)};
  unsigned o[4];
#pragma unroll
  for (int qq = 0; qq < 4; qq++) {
    float v0 = di * a[2 * qq] + sf[2 * qq] * di * di + bias[j8 + 2 * qq];
    float v1 = di * a[2 * qq + 1] + sf[2 * qq + 1] * di * di + bias[j8 + 2 * qq + 1];
    v0 = v0 > 0.f ? v0 : 0.01f * v0;
    v1 = v1 > 0.f ? v1 : 0.01f * v1;
    o[qq] = (unsigned)f2b(v0) | ((unsigned)f2b(v1) << 16);
  }
  *(uint4*)&out[(size_t)i * ld + j8] = *(uint4*)o;
}

// ---------------------------------------------------------------------------
// Row transformer: per-dst softmax, d=128, QKVS concat [N,512] bf16, 1 wave/node
__global__ void attn_row_k(const u16* __restrict__ QKVS, const int* __restrict__ rs,
                           const int* __restrict__ csrc, float* __restrict__ out, int N) {
  int node = blockIdx.x * 4 + (threadIdx.x >> 6);
  if (node >= N) return;
  int lane = threadIdx.x & 63;
  const u16* base = QKVS + (size_t)node * 512;
  unsigned qb = *(const unsigned*)&base[lane * 2];
  float qx = b2f(qb & 0xffff), qy = b2f(qb >> 16);
  int s = rs[node], e = rs[node + 1];
  float m = -1e30f, z = 0.f, ax = 0.f, ay = 0.f;
  const float scale = 0.08838834764831845f;  // 1/sqrt(128)
  for (int p = s; p < e; p++) {
    const u16* kb = QKVS + (size_t)csrc[p] * 512;
    unsigned kw = *(const unsigned*)&kb[128 + lane * 2];
    float part = qx * b2f(kw & 0xffff) + qy * b2f(kw >> 16);
#pragma unroll
    for (int off = 32; off; off >>= 1) part += __shfl_xor(part, off);
    float a = part * scale;
    float mn = fmaxf(m, a);
    float sc = __expf(m - mn);
    float wv = __expf(a - mn);
    z = z * sc + wv;
    unsigned vw = *(const unsigned*)&kb[256 + lane * 2];
    ax = ax * sc + wv * b2f(vw & 0xffff);
    ay = ay * sc + wv * b2f(vw >> 16);
    m = mn;
  }
  float inv = (e == s) ? 0.f : 1.f / (z + 1e-16f);
  unsigned sw = *(const unsigned*)&base[384 + lane * 2];
  out[(size_t)node * 128 + lane * 2] = ax * inv + b2f(sw & 0xffff);
  out[(size_t)node * 128 + lane * 2 + 1] = ay * inv + b2f(sw >> 16);
}

// Col alpha: q[dst].k[src]/16, d=256, QKVS concat [N,1024] bf16, 1 wave/edge
__global__ void col_alpha_k(const u16* __restrict__ QKVS, const int* __restrict__ src,
                            const int* __restrict__ dst, float* __restrict__ alpha, int E) {
  int e = blockIdx.x * 4 + (threadIdx.x >> 6);
  if (e >= E) return;
  int lane = threadIdx.x & 63;
  uint2 qb = *(const uint2*)&QKVS[(size_t)dst[e] * 1024 + lane * 4];
  uint2 kb = *(const uint2*)&QKVS[(size_t)src[e] * 1024 + 256 + lane * 4];
  float p = b2f(qb.x & 0xffff) * b2f(kb.x & 0xffff) + b2f(qb.x >> 16) * b2f(kb.x >> 16) +
            b2f(qb.y & 0xffff) * b2f(kb.y & 0xffff) + b2f(qb.y >> 16) * b2f(kb.y >> 16);
#pragma unroll
  for (int off = 32; off; off >>= 1) p += __shfl_xor(p, off);
  if (lane == 0) alpha[e] = p * 0.0625f;
}

__global__ void stats_k(const float* __restrict__ alpha, int E, double* __restrict__ st) {
  __shared__ double s1[256], s2[256];
  int t = threadIdx.x;
  double a1 = 0, a2 = 0;
  for (int i = blockIdx.x * 256 + t; i < E; i += gridDim.x * 256) {
    double a = alpha[i];
    a1 += a; a2 += a * a;
  }
  s1[t] = a1; s2[t] = a2;
  __syncthreads();
  for (int off = 128; off; off >>= 1) {
    if (t < off) { s1[t] += s1[t + off]; s2[t] += s2[t + off]; }
    __syncthreads();
  }
  if (t == 0) { atomicAdd(&st[0], s1[0]); atomicAdd(&st[1], s2[0]); }
}

// col attention aggregate: writes f32 col_embed (d_out) and bf16 copy
__global__ void col_attn_agg_k(const u16* __restrict__ QKVS, const float* __restrict__ alpha,
                               const int* __restrict__ rs, const int* __restrict__ csrc,
                               const int* __restrict__ ceid, const double* __restrict__ st,
                               float* __restrict__ outf, u16* __restrict__ outb, int E) {
  int i = blockIdx.x;
  int j = threadIdx.x;  // 256 dims
  double mean = st[0] / E;
  double var = (st[1] - E * mean * mean) / (double)(E - 1);
  float rstd = (float)(1.0 / sqrt(var));
  float fm = (float)mean;
  int s = rs[i], e = rs[i + 1];
  float acc = 0.f;
  for (int p = s; p < e; p++) {
    float a = alpha[ceid[p]];
    float x = 3.0f * (a - fm) * rstd;
    float sg = 1.f / (1.f + __expf(-x));
    acc += sg * b2f(QKVS[(size_t)csrc[p] * 1024 + 512 + j]);
  }
  float res = acc + b2f(QKVS[(size_t)i * 1024 + 768 + j]);
  outf[(size_t)i * 256 + j] = res;
  outb[(size_t)i * 256 + j] = f2b(res);
}

// ---------------------------------------------------------------------------
extern "C" void kernel_launch(void* const* d_in, const int* in_sizes, int n_in,
                              void* d_out, int out_size, void* d_ws, size_t ws_size,
                              hipStream_t stream) {
  const float* x      = (const float*)d_in[0];
  const int*   knn_ei = (const int*)d_in[1];
  const int*   ppi_ei = (const int*)d_in[2];
  const float* rl_W   = (const float*)d_in[3];
  const float* rl_b   = (const float*)d_in[4];
  const float* rs_Wl  = (const float*)d_in[5];
  const float* rs_Wr  = (const float*)d_in[6];
  const float* rs_b   = (const float*)d_in[7];
  const float* cs_Wl  = (const float*)d_in[8];
  const float* cs_Wr  = (const float*)d_in[9];
  const float* cs_b   = (const float*)d_in[10];
  const float* rg_W   = (const float*)d_in[11];
  const float* rg_b   = (const float*)d_in[12];
  const float* rq_W   = (const float*)d_in[13];
  const float* rq_b   = (const float*)d_in[14];
  const float* rk_W   = (const float*)d_in[15];
  const float* rk_b   = (const float*)d_in[16];
  const float* rv_W   = (const float*)d_in[17];
  const float* rv_b   = (const float*)d_in[18];
  const float* rsk_W  = (const float*)d_in[19];
  const float* rsk_b  = (const float*)d_in[20];
  const float* cg_W   = (const float*)d_in[21];
  const float* cg_b   = (const float*)d_in[22];
  const float* cq_W   = (const float*)d_in[23];
  const float* cq_b   = (const float*)d_in[24];
  const float* ck_W   = (const float*)d_in[25];
  const float* ck_b   = (const float*)d_in[26];
  const float* cv_W   = (const float*)d_in[27];
  const float* cv_b   = (const float*)d_in[28];
  const float* csk_W  = (const float*)d_in[29];
  const float* csk_b  = (const float*)d_in[30];
  const float* d1_W   = (const float*)d_in[31];
  const float* d1_b   = (const float*)d_in[32];
  const float* d2_W   = (const float*)d_in[33];
  const float* d2_b   = (const float*)d_in[34];
  const float* d3_W   = (const float*)d_in[35];
  const float* d3_b   = (const float*)d_in[36];
  float* out = (float*)d_out;

  char* ws = (char*)d_ws;
  size_t off = 0;
  auto alloc = [&](size_t bytes) -> void* {
    void* p = ws + off;
    off = (off + bytes + 255) & ~(size_t)255;
    return p;
  };
  u16* P0 = (u16*)alloc((size_t)N_GENES * N_CELLS * 2);   // 24.6MB h
  u16* P1 = (u16*)alloc((size_t)N_CELLS * GPAD * 2);      // 25.2MB (CA low half)
  u16* P2 = (u16*)alloc((size_t)N_CELLS * GPAD * 2);      // 25.2MB (CA high half)
  u16* CR = (u16*)alloc((size_t)N_CELLS * 2 * GPAD * 2);  // 50.3MB xb/RA/dec
  u16* BTs = (u16*)alloc((size_t)N_CELLS * 2 * N_CELLS * 2);  // 67.1MB weights
  u16* CEb = (u16*)alloc((size_t)N_CELLS * EMBD_C * 2);
  float* catb = (float*)alloc(1024 * 4);
  int* knn_rs  = (int*)alloc((N_CELLS + 1) * 4);
  int* knn_cnt = (int*)alloc(N_CELLS * 4);
  int* knn_cur = (int*)alloc(N_CELLS * 4);
  int* knn_src = (int*)alloc(KNN_E * 4);
  int* knn_eid = (int*)alloc(KNN_E * 4);
  int* ppi_rs  = (int*)alloc((N_GENES + 1) * 4);
  int* ppi_cnt = (int*)alloc(N_GENES * 4);
  int* ppi_cur = (int*)alloc(N_GENES * 4);
  int* ppi_src = (int*)alloc(PPI_E * 4);
  int* ppi_eid = (int*)alloc(PPI_E * 4);
  float* dinv_knn = (float*)alloc(N_CELLS * 4);
  float* dinv_ppi = (float*)alloc(N_GENES * 4);
  float* alphaB   = (float*)alloc(KNN_E * 4);
  double* stats   = (double*)alloc(2 * 8);
  u16* xb = CR;   // x bf16, dead after h GEMM
  u16* RA = CR;   // row concat [3000][8192]: [ppi-mean | PcoT]
  u16* CA = P1;   // col concat [4096][6144] spans P1+P2 (contiguous allocs)

  auto cvtw = [&](const float* W, int K, int Nw, u16* dst, int ldb, int Kpad) {
    dim3 g((Nw + 31) / 32, (Kpad + 31) / 32);
    cvtw_k<<<g, 256, 0, stream>>>(W, K, Nw, dst, ldb, Kpad);
  };
  auto mg = [&](const u16* A, int lda, const u16* BT, int ldb, const float* bias,
                void* C, int ldc, int M, int N, int K, int accum, int act, int outf32) {
    int nbx = (N + 127) / 128, nby = (M + 127) / 128;
    dim3 g(nbx * nby);
    if (outf32)
      mgemm_k<1><<<g, 256, 0, stream>>>(A, lda, BT, ldb, bias, C, ldc, M, N, K, accum, act, nbx);
    else
      mgemm_k<0><<<g, 256, 0, stream>>>(A, lda, BT, ldb, bias, C, ldc, M, N, K, accum, act, nbx);
  };
  // big GEMMs: 192x256 tile (MF=6) -> 16x16 = 256 blocks for M=3000, N=4096
  auto mg8 = [&](const u16* A, int lda, const u16* BT, int ldb, const float* bias,
                 int biasRow, void* C, int ldc, int M, int N, int K, int act, int outf32) {
    int nbx = (N + 255) / 256, nby = (M + 191) / 192;
    dim3 g(nbx * nby);
    if (outf32)
      mgemm8_k<1, 6><<<g, 512, 0, stream>>>(A, lda, BT, ldb, bias, biasRow, C, ldc,
                                            M, N, K, 0, act, nbx);
    else
      mgemm8_k<0, 6><<<g, 512, 0, stream>>>(A, lda, BT, ldb, bias, biasRow, C, ldc,
                                            M, N, K, 0, act, nbx);
  };
  auto tpad = [&](const u16* in, int R, int C, int lin, u16* o, int ostride, int Rpad) {
    dim3 g((C + 31) / 32, (Rpad + 31) / 32);
    tpad_k<<<g, 256, 0, stream>>>(in, R, C, lin, o, ostride, Rpad);
  };
  auto sage = [&](const u16* X, int ld, const int* rs, const int* csrc, u16* o,
                  int nodes, int D) {
    dim3 g((D / 8 + 255) / 256, nodes);
    sage_agg_k<<<g, 256, 0, stream>>>(X, ld, rs, csrc, o, D);
  };
  auto gcn = [&](const u16* HW, int ld, const int* rs, const int* csrc, const float* dinv,
                 const float* bias, u16* o, int nodes, int D) {
    dim3 g((D / 8 + 255) / 256, nodes);
    gcn_agg_k<<<g, 256, 0, stream>>>(HW, ld, rs, csrc, dinv, bias, o, D);
  };

  // ---- CSR build ----
  zero_i32<<<(N_CELLS + 255) / 256, 256, 0, stream>>>(knn_cnt, N_CELLS);
  count_k<<<(KNN_E + 255) / 256, 256, 0, stream>>>(knn_ei + KNN_E, KNN_E, knn_cnt);
  scan_k<<<1, 1024, 0, stream>>>(knn_cnt, knn_rs, N_CELLS);
  zero_i32<<<(N_CELLS + 255) / 256, 256, 0, stream>>>(knn_cur, N_CELLS);
  fill_k<<<(KNN_E + 255) / 256, 256, 0, stream>>>(knn_ei, knn_ei + KNN_E, KNN_E,
                                                  knn_rs, knn_cur, knn_src, knn_eid);
  dinv_k<<<(N_CELLS + 255) / 256, 256, 0, stream>>>(knn_rs, dinv_knn, N_CELLS);
  zero_i32<<<(N_GENES + 255) / 256, 256, 0, stream>>>(ppi_cnt, N_GENES);
  count_k<<<(PPI_E + 255) / 256, 256, 0, stream>>>(ppi_ei + PPI_E, PPI_E, ppi_cnt);
  scan_k<<<1, 1024, 0, stream>>>(ppi_cnt, ppi_rs, N_GENES);
  zero_i32<<<(N_GENES + 255) / 256, 256, 0, stream>>>(ppi_cur, N_GENES);
  fill_k<<<(PPI_E + 255) / 256, 256, 0, stream>>>(ppi_ei, ppi_ei + PPI_E, PPI_E,
                                                  ppi_rs, ppi_cur, ppi_src, ppi_eid);
  dinv_k<<<(N_GENES + 255) / 256, 256, 0, stream>>>(ppi_rs, dinv_ppi, N_GENES);

  // ---- x -> bf16; h = x @ rl_W + rl_b  [3000,4096] -> P0 ----
  cvtx_k<<<(N_GENES * N_CELLS / 4 + 255) / 256, 256, 0, stream>>>(
      x, xb, N_GENES * N_CELLS);
  cvtw(rl_W, N_CELLS, N_CELLS, BTs, N_CELLS, N_CELLS);
  mg8(xb, N_CELLS, BTs, N_CELLS, rl_b, 0, P0, N_CELLS, N_GENES, N_CELLS, N_CELLS, 0, 0);

  // ---- 2 mutual SAGE layers, Wl/Wr fused via K-concat ----
  for (int i = 0; i < 2; i++) {
    const float* cWl = cs_Wl + (size_t)i * N_GENES * N_GENES;
    const float* cWr = cs_Wr + (size_t)i * N_GENES * N_GENES;
    const float* cb  = cs_b + (size_t)i * N_GENES;
    const float* rWl = rs_Wl + (size_t)i * N_CELLS * N_CELLS;
    const float* rWr = rs_Wr + (size_t)i * N_CELLS * N_CELLS;
    const float* rb  = rs_b + (size_t)i * N_CELLS;
    // CA = [knn-mean(hT) | hT]  [4096][6144] in P1+P2
    tpad(P0, N_GENES, N_CELLS, N_CELLS, CA + GPAD, 2 * GPAD, GPAD);
    sage(CA + GPAD, 2 * GPAD, knn_rs, knn_src, CA, N_CELLS, GPAD);
    cvtw(cWl, N_GENES, N_GENES, BTs, 2 * GPAD, GPAD);
    cvtw(cWr, N_GENES, N_GENES, BTs + GPAD, 2 * GPAD, GPAD);
    // PcoT = leaky(Wcat @ CA^T + cb[row])  [3000][4096] into RA's PcoT slot
    mg8(BTs, 2 * GPAD, CA, 2 * GPAD, cb, 1, RA + N_CELLS, 2 * N_CELLS,
        N_GENES, N_CELLS, 2 * GPAD, 1, 0);
    // RA = [ppi-mean(PcoT) | PcoT]  [3000][8192]
    sage(RA + N_CELLS, 2 * N_CELLS, ppi_rs, ppi_src, RA, N_GENES, N_CELLS);
    cvtw(rWl, N_CELLS, N_CELLS, BTs, 2 * N_CELLS, N_CELLS);
    cvtw(rWr, N_CELLS, N_CELLS, BTs + N_CELLS, 2 * N_CELLS, N_CELLS);
    // h = leaky(RA @ [rWl;rWr]^T + rb)  [3000][4096] -> P0
    mg8(RA, 2 * N_CELLS, BTs, 2 * N_CELLS, rb, 0, P0, N_CELLS,
        N_GENES, N_CELLS, 2 * N_CELLS, 1, 0);
  }

  // ---- row (gene) encoder ----
  cvtw(rg_W, N_CELLS, INTER_R, BTs, N_CELLS, N_CELLS);
  mg(P0, N_CELLS, BTs, N_CELLS, nullptr, P1, INTER_R, N_GENES, INTER_R, N_CELLS, 0, 0, 0);
  gcn(P1, INTER_R, ppi_rs, ppi_src, dinv_ppi, rg_b, P2, N_GENES, INTER_R);
  cvtw(rq_W, INTER_R, EMBD_R, BTs + (size_t)0 * EMBD_R * INTER_R, INTER_R, INTER_R);
  cvtw(rk_W, INTER_R, EMBD_R, BTs + (size_t)1 * EMBD_R * INTER_R, INTER_R, INTER_R);
  cvtw(rv_W, INTER_R, EMBD_R, BTs + (size_t)2 * EMBD_R * INTER_R, INTER_R, INTER_R);
  cvtw(rsk_W, INTER_R, EMBD_R, BTs + (size_t)3 * EMBD_R * INTER_R, INTER_R, INTER_R);
  catbias_k<<<2, 256, 0, stream>>>(rq_b, rk_b, rv_b, rsk_b, EMBD_R, catb);
  mg(P2, INTER_R, BTs, INTER_R, catb, P1, 4 * EMBD_R, N_GENES, 4 * EMBD_R, INTER_R, 0, 0, 0);
  attn_row_k<<<(N_GENES + 3) / 4, 256, 0, stream>>>(P1, ppi_rs, ppi_src, out, N_GENES);

  // ---- col (cell) encoder ----
  tpad(P0, N_GENES, N_CELLS, N_CELLS, P1, GPAD, GPAD);             // hT [4096,3072p]
  cvtw(cg_W, N_GENES, INTER_C, BTs, GPAD, GPAD);
  mg(P1, GPAD, BTs, GPAD, nullptr, P2, INTER_C, N_CELLS, INTER_C, GPAD, 0, 0, 0);
  gcn(P2, INTER_C, knn_rs, knn_src, dinv_knn, cg_b, P0, N_CELLS, INTER_C);
  cvtw(cq_W, INTER_C, EMBD_C, BTs + (size_t)0 * EMBD_C * INTER_C, INTER_C, INTER_C);
  cvtw(ck_W, INTER_C, EMBD_C, BTs + (size_t)1 * EMBD_C * INTER_C, INTER_C, INTER_C);
  cvtw(cv_W, INTER_C, EMBD_C, BTs + (size_t)2 * EMBD_C * INTER_C, INTER_C, INTER_C);
  cvtw(csk_W, INTER_C, EMBD_C, BTs + (size_t)3 * EMBD_C * INTER_C, INTER_C, INTER_C);
  catbias_k<<<4, 256, 0, stream>>>(cq_b, ck_b, cv_b, csk_b, EMBD_C, catb);
  mg(P0, INTER_C, BTs, INTER_C, catb, P1, 4 * EMBD_C, N_CELLS, 4 * EMBD_C, INTER_C, 0, 0, 0);
  col_alpha_k<<<KNN_E / 4, 256, 0, stream>>>(P1, knn_ei, knn_ei + KNN_E, alphaB, KNN_E);
  zero_i32<<<1, 256, 0, stream>>>((int*)stats, 4);
  stats_k<<<64, 256, 0, stream>>>(alphaB, KNN_E, stats);
  float* col_embed = out + (size_t)N_GENES * EMBD_R;
  col_attn_agg_k<<<N_CELLS, 256, 0, stream>>>(P1, alphaB, knn_rs, knn_src, knn_eid,
                                              stats, col_embed, CEb, KNN_E);

  // ---- decoder (temps in CR, free after SAGE loop) ----
  u16* D1 = CR;
  u16* D2 = CR + (size_t)N_CELLS * INTER_C;
  float* recon = col_embed + (size_t)N_CELLS * EMBD_C;
  cvtw(d1_W, EMBD_C, INTER_C, BTs, EMBD_C, EMBD_C);
  mg(CEb, EMBD_C, BTs, EMBD_C, d1_b, D1, INTER_C, N_CELLS, INTER_C, EMBD_C, 0, 2, 0);
  cvtw(d2_W, INTER_C, INTER_C, BTs, INTER_C, INTER_C);
  mg(D1, INTER_C, BTs, INTER_C, d2_b, D2, INTER_C, N_CELLS, INTER_C, INTER_C, 0, 2, 0);
  cvtw(d3_W, INTER_C, N_GENES, BTs, INTER_C, INTER_C);
  mg(D2, INTER_C, BTs, INTER_C, d3_b, recon, N_GENES, N_CELLS, N_GENES, INTER_C, 0, 0, 1);
}